// Round 9
// baseline (294.217 us; speedup 1.0000x reference)
//
#include <hip/hip_runtime.h>
#include <hip/hip_fp16.h>

typedef _Float16 f16x8 __attribute__((ext_vector_type(8)));
typedef float f32x4 __attribute__((ext_vector_type(4)));

__device__ __forceinline__ unsigned short f2h_bits(float f) {
    __half h = __float2half(f);
    return *reinterpret_cast<unsigned short*>(&h);
}
__device__ __forceinline__ float h2f_bits(unsigned short u) {
    __half h = *reinterpret_cast<__half*>(&u);
    return __half2float(h);
}

// acc += a(f32) * f16_lo(hw)  -- one VOP3P v_fma_mix_f32
__device__ __forceinline__ void fma_mix_lo(float& acc, float a, unsigned hw) {
    asm("v_fma_mix_f32 %0, %1, %2, %0 op_sel_hi:[0,1,0]"
        : "+v"(acc) : "v"(a), "v"(hw));
}
// acc += a(f32) * f16_hi(hw)
__device__ __forceinline__ void fma_mix_hi(float& acc, float a, unsigned hw) {
    asm("v_fma_mix_f32 %0, %1, %2, %0 op_sel:[0,1,0] op_sel_hi:[0,1,0]"
        : "+v"(acc) : "v"(a), "v"(hw));
}

// fast ELU: x>0 ? x : e^x-1  (exp never NaN; select discards the inf branch)
__device__ __forceinline__ float elu_fast(float v) {
    float e = __expf(v) - 1.f;
    return v > 0.f ? v : e;
}

// async 16B global->LDS (DMA path, no VGPR round-trip). LDS dest is
// wave-uniform base + lane*16 (HW rule) -- layout below is linear in lane order.
__device__ __forceinline__ void gload_lds16(const void* g, void* l) {
    __builtin_amdgcn_global_load_lds(
        (const __attribute__((address_space(1))) unsigned int*)g,
        (__attribute__((address_space(3))) unsigned int*)l, 16, 0, 0);
}

// ---------------- prep: W transposes (fp16), x cvt, csr=-1 init, deg hist ----
// deg (+ als1/ald1/als2/ald2 atomic-accumulator buffers) are zeroed by a
// preceding hipMemsetAsync (stream-ordered, one contiguous span).
__global__ void k_prep(const float* __restrict__ W1, unsigned short* __restrict__ W1T,
                       const float* __restrict__ W2, unsigned short* __restrict__ W2T,
                       const float* __restrict__ W3, unsigned short* __restrict__ W3T,
                       const float* __restrict__ x, unsigned short* __restrict__ xb,
                       int* __restrict__ csr, int Mcap,
                       const int* __restrict__ ei, int E, int* __restrict__ deg,
                       int DIN, int HC, int DOUT, int N)
{
    int i = blockIdx.x * blockDim.x + threadIdx.x;
    int n1 = DIN * HC;
    int n2 = n1 + HC * HC;
    int n3 = n2 + HC * DOUT;
    int n4 = n3 + N * DIN;
    int n5 = n4 + Mcap;
    int n6 = n5 + E;
    if (i < n1) {
        int k = i / HC, n = i - k * HC;
        W1T[n * DIN + k] = f2h_bits(W1[i]);
    } else if (i < n2) {
        int j = i - n1;
        int k = j / HC, n = j - k * HC;
        W2T[n * HC + k] = f2h_bits(W2[j]);
    } else if (i < n3) {
        int j = i - n2;
        int k = j / DOUT, n = j - k * DOUT;
        W3T[n * HC + k] = f2h_bits(W3[j]);
    } else if (i < n4) {
        int j = i - n3;
        xb[j] = f2h_bits(x[j]);
    } else if (i < n5) {
        csr[i - n4] = -1;           // pad sentinel
    } else if (i < n6) {
        atomicAdd(&deg[ei[E + (i - n5)]], 1);
    }
}

// scan of (deg+1) rounded up to multiple of 4 (padded segments)
__global__ void k_scan(const int* __restrict__ deg, int* __restrict__ off,
                       int* __restrict__ cur, int N) {
    __shared__ int sums[1024];
    int t = threadIdx.x;
    int chunk = (N + 1023) >> 10;
    int lo = t * chunk;
    int hi = lo + chunk; if (hi > N) hi = N;
    if (lo > N) lo = N;
    int s = 0;
    for (int i = lo; i < hi; ++i) s += (deg[i] + 4) & ~3;
    sums[t] = s;
    __syncthreads();
    for (int dd = 1; dd < 1024; dd <<= 1) {
        int v = (t >= dd) ? sums[t - dd] : 0;
        __syncthreads();
        sums[t] += v;
        __syncthreads();
    }
    int run = sums[t] - s;  // exclusive prefix
    for (int i = lo; i < hi; ++i) { off[i] = run; cur[i] = run; run += (deg[i] + 4) & ~3; }
    if (t == 1023) off[N] = run;
}
__global__ void k_fill(const int* __restrict__ ei, int E, int N,
                       int* cur, int* __restrict__ csr) {
    int i = blockIdx.x * blockDim.x + threadIdx.x;
    if (i < E) {
        int s = ei[i], d = ei[E + i];
        int pos = atomicAdd(&cur[d], 1);
        csr[pos] = s;
    } else if (i < E + N) {
        int nn = i - E;
        int pos = atomicAdd(&cur[nn], 1);
        csr[pos] = nn;
    }
}

// ---------------- GEMM (layer 3 / small-Nc path): register-only 64x64, fp16 --
// DOAL: fused attention-logit epilogue (valid only when tiles_n==1, i.e. the
// wave's 64 cols are ALL output cols; layer 3, H=1). Per row:
// al_s[row] = sum_col acc*a_src -> 4 FMA + shfl_xor reduce over the 16 r-lanes.
template <bool OUTH, bool DOAL>
__global__ __launch_bounds__(256) void k_gemm(
    const unsigned short* __restrict__ A, const unsigned short* __restrict__ BT,
    void* __restrict__ D, int M, int K, int Nc, int tiles_n,
    const float* __restrict__ asrc, const float* __restrict__ adst,
    float* __restrict__ als, float* __restrict__ ald)
{
    int wid = blockIdx.x * (blockDim.x >> 6) + (threadIdx.x >> 6);
    int tiles_m = (M + 63) >> 6;
    if (wid >= tiles_m * tiles_n) return;
    int lane = threadIdx.x & 63;
    int tm = wid / tiles_n, tn = wid - tm * tiles_n;
    int m0 = tm << 6, n0 = tn << 6;
    int r = lane & 15, q = lane >> 4;

    const unsigned short* Arow[4];
    const unsigned short* Brow[4];
#pragma unroll
    for (int i = 0; i < 4; ++i) {
        int row = m0 + 16 * i + r; row = row < M ? row : M - 1;
        Arow[i] = A + (size_t)row * K + q * 8;
        Brow[i] = BT + (size_t)(n0 + 16 * i + r) * K + q * 8;
    }

    f32x4 acc[4][4] = {};
    f16x8 a[4], b[4], a2[4], b2[4];
#pragma unroll
    for (int i = 0; i < 4; ++i) {
        a[i] = *(const f16x8*)(Arow[i]);
        b[i] = *(const f16x8*)(Brow[i]);
    }
    for (int k0 = 0; k0 < K; k0 += 32) {
        int kn = k0 + 32;
        if (kn < K) {
#pragma unroll
            for (int i = 0; i < 4; ++i) {
                a2[i] = *(const f16x8*)(Arow[i] + kn);
                b2[i] = *(const f16x8*)(Brow[i] + kn);
            }
        }
#pragma unroll
        for (int i = 0; i < 4; ++i)
#pragma unroll
            for (int j = 0; j < 4; ++j)
                acc[i][j] = __builtin_amdgcn_mfma_f32_16x16x32_f16(a[i], b[j], acc[i][j], 0, 0, 0);
        if (kn < K) {
#pragma unroll
            for (int i = 0; i < 4; ++i) { a[i] = a2[i]; b[i] = b2[i]; }
        }
    }
#pragma unroll
    for (int i = 0; i < 4; ++i) {
        int rowb = m0 + 16 * i + q * 4;
#pragma unroll
        for (int rr = 0; rr < 4; ++rr) {
            int row = rowb + rr;
            if (row < M) {
#pragma unroll
                for (int j = 0; j < 4; ++j) {
                    int col = n0 + 16 * j + r;
                    if (OUTH)
                        ((unsigned short*)D)[(size_t)row * Nc + col] = f2h_bits(acc[i][j][rr]);
                    else
                        ((float*)D)[(size_t)row * Nc + col] = acc[i][j][rr];
                }
            }
        }
    }
    if (DOAL) {
        float asl[4], adl[4];
#pragma unroll
        for (int j = 0; j < 4; ++j) { asl[j] = asrc[16 * j + r]; adl[j] = adst[16 * j + r]; }
#pragma unroll
        for (int i = 0; i < 4; ++i) {
#pragma unroll
            for (int rr = 0; rr < 4; ++rr) {
                float s = 0.f, d = 0.f;
#pragma unroll
                for (int j = 0; j < 4; ++j) {
                    s += acc[i][j][rr] * asl[j];
                    d += acc[i][j][rr] * adl[j];
                }
#pragma unroll
                for (int dd = 1; dd < 16; dd <<= 1) {
                    s += __shfl_xor(s, dd);
                    d += __shfl_xor(d, dd);
                }
                int row = m0 + 16 * i + q * 4 + rr;
                if (r == 0 && row < M) { als[row] = s; ald[row] = d; }
            }
        }
    }
}

// ---------------- GEMM (layers 1&2): 128x64 tile, 2-PHASE dbuf prefetch -----
// 4 waves (2x2), wave tile 64x32, BK=32, double-buffered LDS (24 KiB).
// Schedule per K-step: issue next-tile global_load_lds FIRST, then ds_read +
// MFMA on the current buffer, then ONE __syncthreads (drains only residual
// DMA latency -- the old stage->barrier->compute order gave the DMA zero
// compute overlap, the binding cost at 2.5 blocks/CU; T3-minimum, rule #23).
// AL-FUSION (R8): each 64-col tile's epilogue computes its partial
// Sum(acc * a_src) per row in f32 and atomicAdds into als/ald (zeroed
// upfront) -- kills the k_al dispatches without the R8 extra-tile cost.
__global__ __launch_bounds__(256) void k_gemm_lds(
    const unsigned short* __restrict__ A, const unsigned short* __restrict__ BT,
    unsigned short* __restrict__ D, int M, int K, int Nc, int tiles_n,
    const float* __restrict__ asrc, const float* __restrict__ adst,
    float* __restrict__ als, float* __restrict__ ald)
{
    __shared__ unsigned short As[2][128 * 32];   // 2 x 8 KiB
    __shared__ unsigned short Bs[2][64 * 32];    // 2 x 4 KiB
    int tm = blockIdx.x / tiles_n, tn = blockIdx.x - tm * tiles_n;
    int m0 = tm << 7, n0 = tn << 6;
    int tid = threadIdx.x;
    int w = tid >> 6, lane = tid & 63;
    int wr = w >> 1, wc = w & 1;
    int r = lane & 15, q = lane >> 4;

    // staging: chunk c = 16 tile-rows; lane l -> row c*16 + l/4, bytes (l&3)*16
    int lrow = lane >> 2;
    int lch = (lane & 3) * 8;                  // in fp16 elements
    int ga0 = m0 + w * 16 + lrow;       if (ga0 >= M) ga0 = M - 1;
    int ga1 = m0 + (w + 4) * 16 + lrow; if (ga1 >= M) ga1 = M - 1;
    const unsigned short* pa0 = A + (size_t)ga0 * K + lch;
    const unsigned short* pa1 = A + (size_t)ga1 * K + lch;
    const unsigned short* pb  = BT + (size_t)(n0 + w * 16 + lrow) * K + lch;

    auto stage = [&](int buf, int k0) {
        gload_lds16(pa0 + k0, &As[buf][w * 512]);
        gload_lds16(pa1 + k0, &As[buf][(w + 4) * 512]);
        gload_lds16(pb + k0, &Bs[buf][w * 512]);
    };

    f32x4 acc[4][2] = {};
    stage(0, 0);
    __syncthreads();
    int cur = 0;
    for (int k0 = 0; k0 < K; k0 += 32) {
        if (k0 + 32 < K) stage(cur ^ 1, k0 + 32);   // DMA in flight over compute
        const unsigned short* arp = &As[cur][(wr * 64 + r) * 32 + q * 8];
        const unsigned short* brp = &Bs[cur][(wc * 32 + r) * 32 + q * 8];
        f16x8 a[4], b[2];
#pragma unroll
        for (int i = 0; i < 4; ++i) a[i] = *(const f16x8*)(arp + i * 16 * 32);
#pragma unroll
        for (int j = 0; j < 2; ++j) b[j] = *(const f16x8*)(brp + j * 16 * 32);
#pragma unroll
        for (int i = 0; i < 4; ++i)
#pragma unroll
            for (int j = 0; j < 2; ++j)
                acc[i][j] = __builtin_amdgcn_mfma_f32_16x16x32_f16(a[i], b[j], acc[i][j], 0, 0, 0);
        __syncthreads();          // drains residual DMA + protects buffer swap
        cur ^= 1;
    }

    // ---- D write ----
#pragma unroll
    for (int i = 0; i < 4; ++i) {
        int rowb = m0 + wr * 64 + 16 * i + q * 4;
#pragma unroll
        for (int rr = 0; rr < 4; ++rr) {
            int row = rowb + rr;
            if (row < M) {
#pragma unroll
                for (int j = 0; j < 2; ++j) {
                    int col = n0 + wc * 32 + 16 * j + r;
                    D[(size_t)row * Nc + col] = f2h_bits(acc[i][j][rr]);
                }
            }
        }
    }
    // ---- al partials: this tile's 64 cols belong to head n0>>7 ----
    int head = n0 >> 7;
    int cbase = head * 128 + (n0 & 127) + wc * 32 + r;
    float asl0 = asrc[cbase], asl1 = asrc[cbase + 16];
    float adl0 = adst[cbase], adl1 = adst[cbase + 16];
#pragma unroll
    for (int i = 0; i < 4; ++i)
#pragma unroll
        for (int rr = 0; rr < 4; ++rr) {
            float s = acc[i][0][rr] * asl0 + acc[i][1][rr] * asl1;
            float d = acc[i][0][rr] * adl0 + acc[i][1][rr] * adl1;
#pragma unroll
            for (int dd = 1; dd < 16; dd <<= 1) {
                s += __shfl_xor(s, dd);
                d += __shfl_xor(d, dd);
            }
            int row = m0 + wr * 64 + 16 * i + q * 4 + rr;
            if (r == 0 && row < M) {
                atomicAdd(&als[row * 4 + head], s);
                atomicAdd(&ald[row * 4 + head], d);
            }
        }
}

// ---------------- aggr HC=512 H=4: (node,head) slab, prepass, LDS csr ------
// Wave = (node, head); head-major grid keeps each XCD's h-gather window to a
// 2.56MB head plane (L2-resident; R2: 86% L2 hit). Per 64-edge chunk: PREPASS
// computes alpha(e,head) once per edge (coalesced csr load, 4B als gather,
// wave-uniform ald, 1 exp) and stages BOTH alpha and pre-clamped csr in LDS;
// QUAD loop reads int4 csr + f32x4 alpha via broadcast ds_read. Epilogue ELU
// via exp-1+select (R7: the expm1f expansion was ~200 insts/wave).
template <bool DOELU>
__global__ __launch_bounds__(256) void k_aggr4f(
    const unsigned short* __restrict__ h, const float* __restrict__ als,
    const float* __restrict__ ald,
    const int* __restrict__ off, const int* __restrict__ csr,
    const float* __restrict__ bias,
    unsigned short* __restrict__ outp, int N, int nodeBlocks)
{
    __shared__ float alpS[4][64];     // [wave][edge-in-chunk], 1 KiB
    __shared__ int   csrS[4][64];     // pre-clamped sources, 1 KiB
    int head = blockIdx.x / nodeBlocks;
    int nb = blockIdx.x - head * nodeBlocks;
    int wid = threadIdx.x >> 6;
    int n = nb * 4 + wid;
    if (n >= N) return;
    int lane = threadIdx.x & 63;
    int g = lane >> 4;                // edge group 0..3
    int p = lane & 15;                // channel-lane within group

    int off0 = off[n];
    int degp = off[n + 1] - off0;     // multiple of 4 (padded)
    float aldh = ald[n * 4 + head];
    const char* hB = (const char*)h;
    const unsigned offp = (unsigned)(head * 256 + p * 16);   // bytes within row

    float acc[8] = {};
    float den = 0.f;

    for (int base = 0; base < degp; base += 64) {
        // ---- prepass: one alpha per edge at this head; clamp csr once ----
        float av = 0.f;
        int sc = 0;
        int e = base + lane;
        if (e < degp) {
            int s = csr[off0 + e];
            if (s >= 0) {
                sc = s;
                float l = als[(size_t)(unsigned)s * 4 + head] + aldh;
                l = l > 0.f ? l : 0.2f * l;
                av = __expf(l);
            }
        }
        alpS[wid][lane] = av;
        csrS[wid][lane] = sc;
        // single-wave LDS producer->consumer: DS pipe is in-order per wave

        // ---- quad loop: groups split the (up to) 16 quads of this chunk ----
        int qn = (degp - base) >> 2; if (qn > 16) qn = 16;
        for (int qq = g; qq < qn; qq += 4) {
            int4 cs = *(const int4*)&csrS[wid][qq * 4];
            f32x4 af = *(const f32x4*)&alpS[wid][qq * 4];
            uint4 h0 = *(const uint4*)(hB + (size_t)((((unsigned)cs.x) << 10) + offp));
            uint4 h1 = *(const uint4*)(hB + (size_t)((((unsigned)cs.y) << 10) + offp));
            uint4 h2 = *(const uint4*)(hB + (size_t)((((unsigned)cs.z) << 10) + offp));
            uint4 h3 = *(const uint4*)(hB + (size_t)((((unsigned)cs.w) << 10) + offp));
            den += (af[0] + af[1]) + (af[2] + af[3]);
            unsigned w0[4] = {h0.x, h0.y, h0.z, h0.w};
            unsigned w1[4] = {h1.x, h1.y, h1.z, h1.w};
            unsigned w2[4] = {h2.x, h2.y, h2.z, h2.w};
            unsigned w3[4] = {h3.x, h3.y, h3.z, h3.w};
#pragma unroll
            for (int wv = 0; wv < 4; ++wv) {
                fma_mix_lo(acc[2 * wv],     af[0], w0[wv]);
                fma_mix_hi(acc[2 * wv + 1], af[0], w0[wv]);
            }
#pragma unroll
            for (int wv = 0; wv < 4; ++wv) {
                fma_mix_lo(acc[2 * wv],     af[1], w1[wv]);
                fma_mix_hi(acc[2 * wv + 1], af[1], w1[wv]);
            }
#pragma unroll
            for (int wv = 0; wv < 4; ++wv) {
                fma_mix_lo(acc[2 * wv],     af[2], w2[wv]);
                fma_mix_hi(acc[2 * wv + 1], af[2], w2[wv]);
            }
#pragma unroll
            for (int wv = 0; wv < 4; ++wv) {
                fma_mix_lo(acc[2 * wv],     af[3], w3[wv]);
                fma_mix_hi(acc[2 * wv + 1], af[3], w3[wv]);
            }
        }
    }

    den += __shfl_xor(den, 16);
    den += __shfl_xor(den, 32);
#pragma unroll
    for (int j = 0; j < 8; ++j) {
        acc[j] += __shfl_xor(acc[j], 16);
        acc[j] += __shfl_xor(acc[j], 32);
    }

    if (g == 0) {
        float inv = 1.f / den;
        int cb = head * 128 + p * 8;
        unsigned ww[4];
#pragma unroll
        for (int wv = 0; wv < 4; ++wv) {
            float v0 = acc[2 * wv] * inv + bias[cb + 2 * wv];
            float v1 = acc[2 * wv + 1] * inv + bias[cb + 2 * wv + 1];
            if (DOELU) {
                v0 = elu_fast(v0);
                v1 = elu_fast(v1);
            }
            ww[wv] = (unsigned)f2h_bits(v0) | ((unsigned)f2h_bits(v1) << 16);
        }
        uint4 o; o.x = ww[0]; o.y = ww[1]; o.z = ww[2]; o.w = ww[3];
        *((uint4*)(outp + (size_t)n * 512 + cb)) = o;
    }
}

// ---------------- layer-3 aggr (HC=64, H=1, fp16 h): prepass + LDS csr ----
__global__ __launch_bounds__(256) void k_aggr1c(
    const unsigned short* __restrict__ h, const float* __restrict__ als,
    const float* __restrict__ aldv, const int* __restrict__ off,
    const int* __restrict__ csr, const float* __restrict__ bias,
    float* __restrict__ outp, int N)
{
    __shared__ float alpS[4][64];
    __shared__ int   csrS[4][64];
    int wid = threadIdx.x >> 6;
    int n = blockIdx.x * 4 + wid;
    if (n >= N) return;
    int lane = threadIdx.x & 63;
    int g = lane >> 4;
    int p = lane & 15;

    int off0 = off[n];
    int degp = off[n + 1] - off0;
    float aldh = aldv[n];
    const char* hB = (const char*)h;
    const unsigned offp = (unsigned)(p * 8);   // bytes; lane owns 4 fp16 (8B)

    float acc[4] = {};
    float den = 0.f;

    for (int base = 0; base < degp; base += 64) {
        float av = 0.f;
        int sc = 0;
        int e = base + lane;
        if (e < degp) {
            int s = csr[off0 + e];
            if (s >= 0) {
                sc = s;
                float l = als[s] + aldh;
                l = l > 0.f ? l : 0.2f * l;
                av = __expf(l);
            }
        }
        alpS[wid][lane] = av;
        csrS[wid][lane] = sc;

        int qn = (degp - base) >> 2; if (qn > 16) qn = 16;
        for (int qq = g; qq < qn; qq += 4) {
            int4 cs = *(const int4*)&csrS[wid][qq * 4];
            f32x4 af = *(const f32x4*)&alpS[wid][qq * 4];
            uint2 h0 = *(const uint2*)(hB + (size_t)((((unsigned)cs.x) << 7) + offp));
            uint2 h1 = *(const uint2*)(hB + (size_t)((((unsigned)cs.y) << 7) + offp));
            uint2 h2 = *(const uint2*)(hB + (size_t)((((unsigned)cs.z) << 7) + offp));
            uint2 h3 = *(const uint2*)(hB + (size_t)((((unsigned)cs.w) << 7) + offp));
            den += (af[0] + af[1]) + (af[2] + af[3]);
            fma_mix_lo(acc[0], af[0], h0.x);
            fma_mix_hi(acc[1], af[0], h0.x);
            fma_mix_lo(acc[2], af[0], h0.y);
            fma_mix_hi(acc[3], af[0], h0.y);
            fma_mix_lo(acc[0], af[1], h1.x);
            fma_mix_hi(acc[1], af[1], h1.x);
            fma_mix_lo(acc[2], af[1], h1.y);
            fma_mix_hi(acc[3], af[1], h1.y);
            fma_mix_lo(acc[0], af[2], h2.x);
            fma_mix_hi(acc[1], af[2], h2.x);
            fma_mix_lo(acc[2], af[2], h2.y);
            fma_mix_hi(acc[3], af[2], h2.y);
            fma_mix_lo(acc[0], af[3], h3.x);
            fma_mix_hi(acc[1], af[3], h3.x);
            fma_mix_lo(acc[2], af[3], h3.y);
            fma_mix_hi(acc[3], af[3], h3.y);
        }
    }

    den += __shfl_xor(den, 16);
    den += __shfl_xor(den, 32);
#pragma unroll
    for (int j = 0; j < 4; ++j) {
        acc[j] += __shfl_xor(acc[j], 16);
        acc[j] += __shfl_xor(acc[j], 32);
    }
    if (g == 0) {
        float inv = 1.f / den;
        f32x4 o;
#pragma unroll
        for (int j = 0; j < 4; ++j)
            o[j] = acc[j] * inv + bias[p * 4 + j];
        *((f32x4*)(outp + (size_t)n * 64 + p * 4)) = o;
    }
}

// --------------------------------------------------------------------------
extern "C" void kernel_launch(void* const* d_in, const int* in_sizes, int n_in,
                              void* d_out, int out_size, void* d_ws, size_t ws_size,
                              hipStream_t stream)
{
    const float* x   = (const float*)d_in[0];
    const int*   ei  = (const int*)d_in[1];
    const float* W1  = (const float*)d_in[2];
    const float* as1 = (const float*)d_in[3];
    const float* ad1 = (const float*)d_in[4];
    const float* b1  = (const float*)d_in[5];
    const float* W2  = (const float*)d_in[6];
    const float* as2 = (const float*)d_in[7];
    const float* ad2 = (const float*)d_in[8];
    const float* b2  = (const float*)d_in[9];
    const float* W3  = (const float*)d_in[10];
    const float* as3 = (const float*)d_in[11];
    const float* ad3 = (const float*)d_in[12];
    const float* b3  = (const float*)d_in[13];

    const int DIN = 256, HC = 512, DOUT = 64;
    int N = in_sizes[0] / DIN;
    int E = in_sizes[1] / 2;
    int Mcap = E + 4 * N;  // capacity for 4-padded CSR

    // workspace carve-up
    char* w = (char*)d_ws;
    auto alloc = [&](size_t bytes) -> char* {
        char* p = w;
        w += (bytes + 255) & ~(size_t)255;
        return p;
    };
    // deg + atomic al buffers first, contiguous -> ONE upfront memset
    int* deg    = (int*)alloc((size_t)N * 4);
    float* als1 = (float*)alloc((size_t)N * 4 * 4);
    float* ald1 = (float*)alloc((size_t)N * 4 * 4);
    float* als2 = (float*)alloc((size_t)N * 4 * 4);
    float* ald2 = (float*)alloc((size_t)N * 4 * 4);
    char* zend  = w;                       // end of zeroed span
    int* cur    = (int*)alloc((size_t)N * 4);
    int* off    = (int*)alloc((size_t)(N + 1) * 4);
    int* csr    = (int*)alloc((size_t)Mcap * 4);
    unsigned short* W1T = (unsigned short*)alloc((size_t)HC * DIN * 2);
    unsigned short* W2T = (unsigned short*)alloc((size_t)HC * HC * 2);
    unsigned short* W3T = (unsigned short*)alloc((size_t)DOUT * HC * 2);
    unsigned short* xb  = (unsigned short*)alloc((size_t)N * DIN * 2);
    unsigned short* act = (unsigned short*)alloc((size_t)N * HC * 2);
    unsigned short* hb  = (unsigned short*)alloc((size_t)N * HC * 2);
    unsigned short* hb3 = (unsigned short*)alloc((size_t)N * DOUT * 2);  // fp16 h (layer 3)
    float* als3 = (float*)alloc((size_t)N * 4);
    float* ald3 = (float*)alloc((size_t)N * 4);

    // ---- build: memset(deg+al accums) -> prep -> scan -> fill ----
    hipMemsetAsync(deg, 0, (size_t)(zend - (char*)deg), stream);
    int prep_total = DIN * HC + HC * HC + HC * DOUT + N * DIN + Mcap + E;
    k_prep<<<(prep_total + 255) / 256, 256, 0, stream>>>(
        W1, W1T, W2, W2T, W3, W3T, x, xb, csr, Mcap, ei, E, deg, DIN, HC, DOUT, N);
    k_scan<<<1, 1024, 0, stream>>>(deg, off, cur, N);
    k_fill<<<(E + N + 255) / 256, 256, 0, stream>>>(ei, E, N, cur, csr);

    int tiles_m = (N + 63) / 64;
    auto gemm_blocks = [&](int tn) { return (tiles_m * tn + 3) / 4; };
    int tm128 = (N + 127) / 128;
    int tiles_n8 = HC / 64;            // 8 data tiles, al fused via atomics
    int nwave_blocks = (N + 3) / 4;
    int nodeBlocks = (N + 3) / 4;

    // ---- layer 1 ----
    k_gemm_lds<<<tm128 * tiles_n8, 256, 0, stream>>>(
        xb, W1T, hb, N, DIN, HC, tiles_n8, as1, ad1, als1, ald1);
    k_aggr4f<true><<<4 * nodeBlocks, 256, 0, stream>>>(hb, als1, ald1, off, csr, b1, act, N, nodeBlocks);

    // ---- layer 2 ----
    k_gemm_lds<<<tm128 * tiles_n8, 256, 0, stream>>>(
        act, W2T, hb, N, HC, HC, tiles_n8, as2, ad2, als2, ald2);
    k_aggr4f<true><<<4 * nodeBlocks, 256, 0, stream>>>(hb, als2, ald2, off, csr, b2, act, N, nodeBlocks);

    // ---- layer 3 (fp16 h path; Nc=64, al fused into GEMM epilogue) ----
    k_gemm<true, true><<<gemm_blocks(1), 256, 0, stream>>>(
        act, W3T, hb3, N, HC, DOUT, 1, as3, ad3, als3, ald3);
    k_aggr1c<<<nwave_blocks, 256, 0, stream>>>(hb3, als3, ald3, off, csr, b3, (float*)d_out, N);
}

// Round 10
// 254.554 us; speedup vs baseline: 1.1558x; 1.1558x over previous
//
#include <hip/hip_runtime.h>
#include <hip/hip_fp16.h>

typedef _Float16 f16x8 __attribute__((ext_vector_type(8)));
typedef float f32x4 __attribute__((ext_vector_type(4)));

__device__ __forceinline__ unsigned short f2h_bits(float f) {
    __half h = __float2half(f);
    return *reinterpret_cast<unsigned short*>(&h);
}
__device__ __forceinline__ float h2f_bits(unsigned short u) {
    __half h = *reinterpret_cast<__half*>(&u);
    return __half2float(h);
}

// acc += a(f32) * f16_lo(hw)  -- one VOP3P v_fma_mix_f32
__device__ __forceinline__ void fma_mix_lo(float& acc, float a, unsigned hw) {
    asm("v_fma_mix_f32 %0, %1, %2, %0 op_sel_hi:[0,1,0]"
        : "+v"(acc) : "v"(a), "v"(hw));
}
// acc += a(f32) * f16_hi(hw)
__device__ __forceinline__ void fma_mix_hi(float& acc, float a, unsigned hw) {
    asm("v_fma_mix_f32 %0, %1, %2, %0 op_sel:[0,1,0] op_sel_hi:[0,1,0]"
        : "+v"(acc) : "v"(a), "v"(hw));
}

// fast ELU: x>0 ? x : e^x-1  (exp never NaN; select discards the inf branch)
__device__ __forceinline__ float elu_fast(float v) {
    float e = __expf(v) - 1.f;
    return v > 0.f ? v : e;
}

// async 16B global->LDS (DMA path, no VGPR round-trip). LDS dest is
// wave-uniform base + lane*16 (HW rule) -- layout below is linear in lane order.
__device__ __forceinline__ void gload_lds16(const void* g, void* l) {
    __builtin_amdgcn_global_load_lds(
        (const __attribute__((address_space(1))) unsigned int*)g,
        (__attribute__((address_space(3))) unsigned int*)l, 16, 0, 0);
}

// ---------------- prep: W transposes (fp16) + was/wad fold, x cvt, csr, deg --
// was[k,h] = sum_c W[k,128h+c]*a_src[h,c] (f32 math, fp16 store): attention
// logits become 8 extra GEMM columns (R8 structure, measured 263.6).
// deg (+tot) zeroed by a preceding hipMemsetAsync (stream-ordered).
__global__ void k_prep(const float* __restrict__ W1, unsigned short* __restrict__ W1T,
                       const float* __restrict__ W2, unsigned short* __restrict__ W2T,
                       const float* __restrict__ W3, unsigned short* __restrict__ W3T,
                       const float* __restrict__ x, unsigned short* __restrict__ xb,
                       int* __restrict__ csr, int Mcap,
                       const int* __restrict__ ei, int E, int* __restrict__ deg,
                       const float* __restrict__ as1, const float* __restrict__ ad1,
                       const float* __restrict__ as2, const float* __restrict__ ad2,
                       int DIN, int HC, int DOUT, int N)
{
    int i = blockIdx.x * blockDim.x + threadIdx.x;
    int n1 = DIN * HC;
    int n2 = n1 + HC * HC;
    int n3 = n2 + HC * DOUT;
    int n4 = n3 + N * DIN;
    int n5 = n4 + Mcap;
    int n6 = n5 + E;
    int n7 = n6 + 8 * DIN;               // was1/wad1
    int n8 = n7 + 8 * HC;                // was2/wad2
    int n9 = n8 + 56 * DIN + 56 * HC;    // zero pad rows 520..575
    if (i < n1) {
        int k = i / HC, n = i - k * HC;
        W1T[n * DIN + k] = f2h_bits(W1[i]);
    } else if (i < n2) {
        int j = i - n1;
        int k = j / HC, n = j - k * HC;
        W2T[n * HC + k] = f2h_bits(W2[j]);
    } else if (i < n3) {
        int j = i - n2;
        int k = j / DOUT, n = j - k * DOUT;
        W3T[n * HC + k] = f2h_bits(W3[j]);
    } else if (i < n4) {
        int j = i - n3;
        xb[j] = f2h_bits(x[j]);
    } else if (i < n5) {
        csr[i - n4] = -1;           // pad sentinel
    } else if (i < n6) {
        atomicAdd(&deg[ei[E + (i - n5)]], 1);
    } else if (i < n7) {
        int j = i - n6;
        int h8 = j / DIN, k = j - h8 * DIN;
        int hh = h8 & 3;
        const float* av = (h8 < 4 ? as1 : ad1) + hh * 128;
        const float* wr = W1 + (size_t)k * HC + hh * 128;
        float s = 0.f;
        for (int c = 0; c < 128; ++c) s += wr[c] * av[c];
        W1T[(size_t)(HC + h8) * DIN + k] = f2h_bits(s);
    } else if (i < n8) {
        int j = i - n7;
        int h8 = j / HC, k = j - h8 * HC;
        int hh = h8 & 3;
        const float* av = (h8 < 4 ? as2 : ad2) + hh * 128;
        const float* wr = W2 + (size_t)k * HC + hh * 128;
        float s = 0.f;
        for (int c = 0; c < 128; ++c) s += wr[c] * av[c];
        W2T[(size_t)(HC + h8) * HC + k] = f2h_bits(s);
    } else if (i < n9) {
        int j = i - n8;
        if (j < 56 * DIN) W1T[(size_t)(HC + 8) * DIN + j] = 0;
        else              W2T[(size_t)(HC + 8) * HC + (j - 56 * DIN)] = 0;
    }
}

// ---------------- parallel segment allocator (replaces serial k_scan) ------
// Segment ORDER is irrelevant (aggr derives length from deg[n]); per-wave
// inclusive shfl-scan + ONE atomicAdd per wave (157 total) assigns bases.
// R9: the old single-workgroup scan serialized ~20 barrier rounds on 1 CU.
__global__ void k_alloc(const int* __restrict__ deg, int* __restrict__ off,
                        int* __restrict__ cur, int* __restrict__ tot, int N)
{
    int i = blockIdx.x * blockDim.x + threadIdx.x;
    int lane = threadIdx.x & 63;
    int sz = (i < N) ? ((deg[i] + 4) & ~3) : 0;
    int run = sz;
#pragma unroll
    for (int d = 1; d < 64; d <<= 1) {
        int v = __shfl_up(run, d);
        if (lane >= d) run += v;
    }
    int wtot = __shfl(run, 63);
    int base = 0;
    if (lane == 63) base = atomicAdd(tot, wtot);
    base = __shfl(base, 63);
    if (i < N) {
        int p = base + run - sz;   // exclusive within wave
        off[i] = p;
        cur[i] = p;
    }
}

__global__ void k_fill(const int* __restrict__ ei, int E, int N,
                       int* cur, int* __restrict__ csr) {
    int i = blockIdx.x * blockDim.x + threadIdx.x;
    if (i < E) {
        int s = ei[i], d = ei[E + i];
        int pos = atomicAdd(&cur[d], 1);
        csr[pos] = s;
    } else if (i < E + N) {
        int nn = i - E;
        int pos = atomicAdd(&cur[nn], 1);
        csr[pos] = nn;
    }
}

// ---------------- GEMM (layer 3 / small-Nc path): register-only 64x64, fp16 --
// DOAL: fused attention-logit epilogue (valid only when tiles_n==1, i.e. the
// wave's 64 cols are ALL output cols; layer 3, H=1). Per row:
// al_s[row] = sum_col acc*a_src -> 4 FMA + shfl_xor reduce over the 16 r-lanes.
template <bool OUTH, bool DOAL>
__global__ __launch_bounds__(256) void k_gemm(
    const unsigned short* __restrict__ A, const unsigned short* __restrict__ BT,
    void* __restrict__ D, int M, int K, int Nc, int tiles_n,
    const float* __restrict__ asrc, const float* __restrict__ adst,
    float* __restrict__ als, float* __restrict__ ald)
{
    int wid = blockIdx.x * (blockDim.x >> 6) + (threadIdx.x >> 6);
    int tiles_m = (M + 63) >> 6;
    if (wid >= tiles_m * tiles_n) return;
    int lane = threadIdx.x & 63;
    int tm = wid / tiles_n, tn = wid - tm * tiles_n;
    int m0 = tm << 6, n0 = tn << 6;
    int r = lane & 15, q = lane >> 4;

    const unsigned short* Arow[4];
    const unsigned short* Brow[4];
#pragma unroll
    for (int i = 0; i < 4; ++i) {
        int row = m0 + 16 * i + r; row = row < M ? row : M - 1;
        Arow[i] = A + (size_t)row * K + q * 8;
        Brow[i] = BT + (size_t)(n0 + 16 * i + r) * K + q * 8;
    }

    f32x4 acc[4][4] = {};
    f16x8 a[4], b[4], a2[4], b2[4];
#pragma unroll
    for (int i = 0; i < 4; ++i) {
        a[i] = *(const f16x8*)(Arow[i]);
        b[i] = *(const f16x8*)(Brow[i]);
    }
    for (int k0 = 0; k0 < K; k0 += 32) {
        int kn = k0 + 32;
        if (kn < K) {
#pragma unroll
            for (int i = 0; i < 4; ++i) {
                a2[i] = *(const f16x8*)(Arow[i] + kn);
                b2[i] = *(const f16x8*)(Brow[i] + kn);
            }
        }
#pragma unroll
        for (int i = 0; i < 4; ++i)
#pragma unroll
            for (int j = 0; j < 4; ++j)
                acc[i][j] = __builtin_amdgcn_mfma_f32_16x16x32_f16(a[i], b[j], acc[i][j], 0, 0, 0);
        if (kn < K) {
#pragma unroll
            for (int i = 0; i < 4; ++i) { a[i] = a2[i]; b[i] = b2[i]; }
        }
    }
#pragma unroll
    for (int i = 0; i < 4; ++i) {
        int rowb = m0 + 16 * i + q * 4;
#pragma unroll
        for (int rr = 0; rr < 4; ++rr) {
            int row = rowb + rr;
            if (row < M) {
#pragma unroll
                for (int j = 0; j < 4; ++j) {
                    int col = n0 + 16 * j + r;
                    if (OUTH)
                        ((unsigned short*)D)[(size_t)row * Nc + col] = f2h_bits(acc[i][j][rr]);
                    else
                        ((float*)D)[(size_t)row * Nc + col] = acc[i][j][rr];
                }
            }
        }
    }
    if (DOAL) {
        float asl[4], adl[4];
#pragma unroll
        for (int j = 0; j < 4; ++j) { asl[j] = asrc[16 * j + r]; adl[j] = adst[16 * j + r]; }
#pragma unroll
        for (int i = 0; i < 4; ++i) {
#pragma unroll
            for (int rr = 0; rr < 4; ++rr) {
                float s = 0.f, d = 0.f;
#pragma unroll
                for (int j = 0; j < 4; ++j) {
                    s += acc[i][j][rr] * asl[j];
                    d += acc[i][j][rr] * adl[j];
                }
#pragma unroll
                for (int dd = 1; dd < 16; dd <<= 1) {
                    s += __shfl_xor(s, dd);
                    d += __shfl_xor(d, dd);
                }
                int row = m0 + 16 * i + q * 4 + rr;
                if (r == 0 && row < M) { als[row] = s; ald[row] = d; }
            }
        }
    }
}

// ---------------- GEMM (layers 1&2): m97-style 128x64 tile, LDS-staged, fp16 --
// 4 waves (2x2), wave tile 64x32, BK=32. Staging via global_load_lds width 16.
// tiles_n = HC/64 + 1: the LAST column-tile multiplies the was/wad extension
// rows of BT (512..519; 520..575 zero), so its accumulators ARE the attention
// logits -- epilogue writes als/ald (f32, exclusive). R8-proven structure
// (263.6); R9's dbuf+atomics variant regressed (+30us) -- see journal.
__global__ __launch_bounds__(256) void k_gemm_lds(
    const unsigned short* __restrict__ A, const unsigned short* __restrict__ BT,
    unsigned short* __restrict__ D, int M, int K, int Nc, int tiles_n,
    float* __restrict__ als, float* __restrict__ ald)
{
    __shared__ unsigned short As[128 * 32];   // 8 KiB
    __shared__ unsigned short Bs[64 * 32];    // 4 KiB
    int tm = blockIdx.x / tiles_n, tn = blockIdx.x - tm * tiles_n;
    int m0 = tm << 7, n0 = tn << 6;
    int tid = threadIdx.x;
    int w = tid >> 6, lane = tid & 63;
    int wr = w >> 1, wc = w & 1;
    int r = lane & 15, q = lane >> 4;

    // staging: chunk c = 16 tile-rows; lane l -> row c*16 + l/4, bytes (l&3)*16
    int lrow = lane >> 2;
    int lch = (lane & 3) * 8;                  // in fp16 elements
    int ga0 = m0 + w * 16 + lrow;       if (ga0 >= M) ga0 = M - 1;
    int ga1 = m0 + (w + 4) * 16 + lrow; if (ga1 >= M) ga1 = M - 1;
    const unsigned short* pa0 = A + (size_t)ga0 * K + lch;
    const unsigned short* pa1 = A + (size_t)ga1 * K + lch;
    const unsigned short* pb  = BT + (size_t)(n0 + w * 16 + lrow) * K + lch;
    unsigned short* lA0 = As + w * 512;        // wave-uniform LDS chunk bases
    unsigned short* lA1 = As + (w + 4) * 512;
    unsigned short* lB  = Bs + w * 512;

    const unsigned short* arp = As + (wr * 64 + r) * 32 + q * 8;
    const unsigned short* brp = Bs + (wc * 32 + r) * 32 + q * 8;

    f32x4 acc[4][2] = {};
    for (int k0 = 0; k0 < K; k0 += 32) {
        gload_lds16(pa0 + k0, lA0);
        gload_lds16(pa1 + k0, lA1);
        gload_lds16(pb + k0, lB);
        __syncthreads();                        // compiler drains vmcnt(0) here
        f16x8 a[4], b[2];
#pragma unroll
        for (int i = 0; i < 4; ++i) a[i] = *(const f16x8*)(arp + i * 16 * 32);
#pragma unroll
        for (int j = 0; j < 2; ++j) b[j] = *(const f16x8*)(brp + j * 16 * 32);
#pragma unroll
        for (int i = 0; i < 4; ++i)
#pragma unroll
            for (int j = 0; j < 2; ++j)
                acc[i][j] = __builtin_amdgcn_mfma_f32_16x16x32_f16(a[i], b[j], acc[i][j], 0, 0, 0);
        __syncthreads();                        // protect LDS before next stage
    }
    if (tn == tiles_n - 1) {
        // al tile: col r (wc==0, j==0) maps to BT row 512+r: r<4 -> als head r,
        // r in 4..7 -> ald head r-4. Exclusive f32 writes, no atomics.
        if (wc == 0 && r < 8) {
            float* dst = (r < 4) ? als : ald;
            int hh = r & 3;
#pragma unroll
            for (int i = 0; i < 4; ++i)
#pragma unroll
                for (int rr = 0; rr < 4; ++rr) {
                    int row = m0 + wr * 64 + 16 * i + q * 4 + rr;
                    if (row < M) dst[row * 4 + hh] = acc[i][0][rr];
                }
        }
        return;
    }
#pragma unroll
    for (int i = 0; i < 4; ++i) {
        int rowb = m0 + wr * 64 + 16 * i + q * 4;
#pragma unroll
        for (int rr = 0; rr < 4; ++rr) {
            int row = rowb + rr;
            if (row < M) {
#pragma unroll
                for (int j = 0; j < 2; ++j) {
                    int col = n0 + wc * 32 + 16 * j + r;
                    D[(size_t)row * Nc + col] = f2h_bits(acc[i][j][rr]);
                }
            }
        }
    }
}

// ---------------- aggr HC=512 H=4: (node,head) slab, prepass, LDS csr ------
// Wave = (node, head); head-major grid keeps each XCD's h-gather window to a
// 2.56MB head plane (L2-resident; R2: 86% L2 hit). Per 64-edge chunk: PREPASS
// computes alpha(e,head) once per edge (coalesced csr load, 4B als gather,
// wave-uniform ald, 1 exp) and stages BOTH alpha and pre-clamped csr in LDS;
// QUAD loop reads int4 csr + f32x4 alpha via broadcast ds_read. Epilogue ELU
// via exp-1+select (R7). Segment length now derived from deg[n] (R10: off is
// an unordered atomic allocation; off[n+1]-off[n] no longer meaningful).
template <bool DOELU>
__global__ __launch_bounds__(256) void k_aggr4f(
    const unsigned short* __restrict__ h, const float* __restrict__ als,
    const float* __restrict__ ald,
    const int* __restrict__ off, const int* __restrict__ deg,
    const int* __restrict__ csr,
    const float* __restrict__ bias,
    unsigned short* __restrict__ outp, int N, int nodeBlocks)
{
    __shared__ float alpS[4][64];     // [wave][edge-in-chunk], 1 KiB
    __shared__ int   csrS[4][64];     // pre-clamped sources, 1 KiB
    int head = blockIdx.x / nodeBlocks;
    int nb = blockIdx.x - head * nodeBlocks;
    int wid = threadIdx.x >> 6;
    int n = nb * 4 + wid;
    if (n >= N) return;
    int lane = threadIdx.x & 63;
    int g = lane >> 4;                // edge group 0..3
    int p = lane & 15;                // channel-lane within group

    int off0 = off[n];
    int degp = (deg[n] + 4) & ~3;     // padded segment length
    float aldh = ald[n * 4 + head];
    const char* hB = (const char*)h;
    const unsigned offp = (unsigned)(head * 256 + p * 16);   // bytes within row

    float acc[8] = {};
    float den = 0.f;

    for (int base = 0; base < degp; base += 64) {
        // ---- prepass: one alpha per edge at this head; clamp csr once ----
        float av = 0.f;
        int sc = 0;
        int e = base + lane;
        if (e < degp) {
            int s = csr[off0 + e];
            if (s >= 0) {
                sc = s;
                float l = als[(size_t)(unsigned)s * 4 + head] + aldh;
                l = l > 0.f ? l : 0.2f * l;
                av = __expf(l);
            }
        }
        alpS[wid][lane] = av;
        csrS[wid][lane] = sc;
        // single-wave LDS producer->consumer: DS pipe is in-order per wave

        // ---- quad loop: groups split the (up to) 16 quads of this chunk ----
        int qn = (degp - base) >> 2; if (qn > 16) qn = 16;
        for (int qq = g; qq < qn; qq += 4) {
            int4 cs = *(const int4*)&csrS[wid][qq * 4];
            f32x4 af = *(const f32x4*)&alpS[wid][qq * 4];
            uint4 h0 = *(const uint4*)(hB + (size_t)((((unsigned)cs.x) << 10) + offp));
            uint4 h1 = *(const uint4*)(hB + (size_t)((((unsigned)cs.y) << 10) + offp));
            uint4 h2 = *(const uint4*)(hB + (size_t)((((unsigned)cs.z) << 10) + offp));
            uint4 h3 = *(const uint4*)(hB + (size_t)((((unsigned)cs.w) << 10) + offp));
            den += (af[0] + af[1]) + (af[2] + af[3]);
            unsigned w0[4] = {h0.x, h0.y, h0.z, h0.w};
            unsigned w1[4] = {h1.x, h1.y, h1.z, h1.w};
            unsigned w2[4] = {h2.x, h2.y, h2.z, h2.w};
            unsigned w3[4] = {h3.x, h3.y, h3.z, h3.w};
#pragma unroll
            for (int wv = 0; wv < 4; ++wv) {
                fma_mix_lo(acc[2 * wv],     af[0], w0[wv]);
                fma_mix_hi(acc[2 * wv + 1], af[0], w0[wv]);
            }
#pragma unroll
            for (int wv = 0; wv < 4; ++wv) {
                fma_mix_lo(acc[2 * wv],     af[1], w1[wv]);
                fma_mix_hi(acc[2 * wv + 1], af[1], w1[wv]);
            }
#pragma unroll
            for (int wv = 0; wv < 4; ++wv) {
                fma_mix_lo(acc[2 * wv],     af[2], w2[wv]);
                fma_mix_hi(acc[2 * wv + 1], af[2], w2[wv]);
            }
#pragma unroll
            for (int wv = 0; wv < 4; ++wv) {
                fma_mix_lo(acc[2 * wv],     af[3], w3[wv]);
                fma_mix_hi(acc[2 * wv + 1], af[3], w3[wv]);
            }
        }
    }

    den += __shfl_xor(den, 16);
    den += __shfl_xor(den, 32);
#pragma unroll
    for (int j = 0; j < 8; ++j) {
        acc[j] += __shfl_xor(acc[j], 16);
        acc[j] += __shfl_xor(acc[j], 32);
    }

    if (g == 0) {
        float inv = 1.f / den;
        int cb = head * 128 + p * 8;
        unsigned ww[4];
#pragma unroll
        for (int wv = 0; wv < 4; ++wv) {
            float v0 = acc[2 * wv] * inv + bias[cb + 2 * wv];
            float v1 = acc[2 * wv + 1] * inv + bias[cb + 2 * wv + 1];
            if (DOELU) {
                v0 = elu_fast(v0);
                v1 = elu_fast(v1);
            }
            ww[wv] = (unsigned)f2h_bits(v0) | ((unsigned)f2h_bits(v1) << 16);
        }
        uint4 o; o.x = ww[0]; o.y = ww[1]; o.z = ww[2]; o.w = ww[3];
        *((uint4*)(outp + (size_t)n * 512 + cb)) = o;
    }
}

// ---------------- layer-3 aggr (HC=64, H=1, fp16 h): prepass + LDS csr ----
__global__ __launch_bounds__(256) void k_aggr1c(
    const unsigned short* __restrict__ h, const float* __restrict__ als,
    const float* __restrict__ aldv, const int* __restrict__ off,
    const int* __restrict__ deg,
    const int* __restrict__ csr, const float* __restrict__ bias,
    float* __restrict__ outp, int N)
{
    __shared__ float alpS[4][64];
    __shared__ int   csrS[4][64];
    int wid = threadIdx.x >> 6;
    int n = blockIdx.x * 4 + wid;
    if (n >= N) return;
    int lane = threadIdx.x & 63;
    int g = lane >> 4;
    int p = lane & 15;

    int off0 = off[n];
    int degp = (deg[n] + 4) & ~3;
    float aldh = aldv[n];
    const char* hB = (const char*)h;
    const unsigned offp = (unsigned)(p * 8);   // bytes; lane owns 4 fp16 (8B)

    float acc[4] = {};
    float den = 0.f;

    for (int base = 0; base < degp; base += 64) {
        float av = 0.f;
        int sc = 0;
        int e = base + lane;
        if (e < degp) {
            int s = csr[off0 + e];
            if (s >= 0) {
                sc = s;
                float l = als[s] + aldh;
                l = l > 0.f ? l : 0.2f * l;
                av = __expf(l);
            }
        }
        alpS[wid][lane] = av;
        csrS[wid][lane] = sc;

        int qn = (degp - base) >> 2; if (qn > 16) qn = 16;
        for (int qq = g; qq < qn; qq += 4) {
            int4 cs = *(const int4*)&csrS[wid][qq * 4];
            f32x4 af = *(const f32x4*)&alpS[wid][qq * 4];
            uint2 h0 = *(const uint2*)(hB + (size_t)((((unsigned)cs.x) << 7) + offp));
            uint2 h1 = *(const uint2*)(hB + (size_t)((((unsigned)cs.y) << 7) + offp));
            uint2 h2 = *(const uint2*)(hB + (size_t)((((unsigned)cs.z) << 7) + offp));
            uint2 h3 = *(const uint2*)(hB + (size_t)((((unsigned)cs.w) << 7) + offp));
            den += (af[0] + af[1]) + (af[2] + af[3]);
            fma_mix_lo(acc[0], af[0], h0.x);
            fma_mix_hi(acc[1], af[0], h0.x);
            fma_mix_lo(acc[2], af[0], h0.y);
            fma_mix_hi(acc[3], af[0], h0.y);
            fma_mix_lo(acc[0], af[1], h1.x);
            fma_mix_hi(acc[1], af[1], h1.x);
            fma_mix_lo(acc[2], af[1], h1.y);
            fma_mix_hi(acc[3], af[1], h1.y);
            fma_mix_lo(acc[0], af[2], h2.x);
            fma_mix_hi(acc[1], af[2], h2.x);
            fma_mix_lo(acc[2], af[2], h2.y);
            fma_mix_hi(acc[3], af[2], h2.y);
            fma_mix_lo(acc[0], af[3], h3.x);
            fma_mix_hi(acc[1], af[3], h3.x);
            fma_mix_lo(acc[2], af[3], h3.y);
            fma_mix_hi(acc[3], af[3], h3.y);
        }
    }

    den += __shfl_xor(den, 16);
    den += __shfl_xor(den, 32);
#pragma unroll
    for (int j = 0; j < 4; ++j) {
        acc[j] += __shfl_xor(acc[j], 16);
        acc[j] += __shfl_xor(acc[j], 32);
    }
    if (g == 0) {
        float inv = 1.f / den;
        f32x4 o;
#pragma unroll
        for (int j = 0; j < 4; ++j)
            o[j] = acc[j] * inv + bias[p * 4 + j];
        *((f32x4*)(outp + (size_t)n * 64 + p * 4)) = o;
    }
}

// --------------------------------------------------------------------------
extern "C" void kernel_launch(void* const* d_in, const int* in_sizes, int n_in,
                              void* d_out, int out_size, void* d_ws, size_t ws_size,
                              hipStream_t stream)
{
    const float* x   = (const float*)d_in[0];
    const int*   ei  = (const int*)d_in[1];
    const float* W1  = (const float*)d_in[2];
    const float* as1 = (const float*)d_in[3];
    const float* ad1 = (const float*)d_in[4];
    const float* b1  = (const float*)d_in[5];
    const float* W2  = (const float*)d_in[6];
    const float* as2 = (const float*)d_in[7];
    const float* ad2 = (const float*)d_in[8];
    const float* b2  = (const float*)d_in[9];
    const float* W3  = (const float*)d_in[10];
    const float* as3 = (const float*)d_in[11];
    const float* ad3 = (const float*)d_in[12];
    const float* b3  = (const float*)d_in[13];

    const int DIN = 256, HC = 512, DOUT = 64;
    const int EXT = 64;                 // was/wad + zero-pad extension rows
    int N = in_sizes[0] / DIN;
    int E = in_sizes[1] / 2;
    int Mcap = E + 4 * N;  // capacity for 4-padded CSR

    // workspace carve-up
    char* w = (char*)d_ws;
    auto alloc = [&](size_t bytes) -> char* {
        char* p = w;
        w += (bytes + 255) & ~(size_t)255;
        return p;
    };
    // deg + tot first, contiguous -> ONE upfront memset
    int* deg    = (int*)alloc((size_t)N * 4);
    int* tot    = (int*)alloc(4);
    char* zend  = w;                       // end of zeroed span
    int* cur    = (int*)alloc((size_t)N * 4);
    int* off    = (int*)alloc((size_t)(N + 1) * 4);
    int* csr    = (int*)alloc((size_t)Mcap * 4);
    unsigned short* W1T = (unsigned short*)alloc((size_t)(HC + EXT) * DIN * 2);
    unsigned short* W2T = (unsigned short*)alloc((size_t)(HC + EXT) * HC * 2);
    unsigned short* W3T = (unsigned short*)alloc((size_t)DOUT * HC * 2);
    unsigned short* xb  = (unsigned short*)alloc((size_t)N * DIN * 2);
    unsigned short* act = (unsigned short*)alloc((size_t)N * HC * 2);
    unsigned short* hb  = (unsigned short*)alloc((size_t)N * HC * 2);
    unsigned short* hb3 = (unsigned short*)alloc((size_t)N * DOUT * 2);  // fp16 h (layer 3)
    float* als   = (float*)alloc((size_t)N * 4 * 4);
    float* ald   = (float*)alloc((size_t)N * 4 * 4);

    // ---- build: memset(deg+tot) -> prep(+was/wad) -> alloc -> fill ----
    hipMemsetAsync(deg, 0, (size_t)(zend - (char*)deg), stream);
    int prep_total = DIN * HC + HC * HC + HC * DOUT + N * DIN + Mcap + E
                   + 8 * DIN + 8 * HC + 56 * DIN + 56 * HC;
    k_prep<<<(prep_total + 255) / 256, 256, 0, stream>>>(
        W1, W1T, W2, W2T, W3, W3T, x, xb, csr, Mcap, ei, E, deg,
        as1, ad1, as2, ad2, DIN, HC, DOUT, N);
    k_alloc<<<(N + 255) / 256, 256, 0, stream>>>(deg, off, cur, tot, N);
    k_fill<<<(E + N + 255) / 256, 256, 0, stream>>>(ei, E, N, cur, csr);

    int tiles_m = (N + 63) / 64;
    auto gemm_blocks = [&](int tn) { return (tiles_m * tn + 3) / 4; };
    int tm128 = (N + 127) / 128;
    int tiles_n12 = HC / 64 + 1;        // 8 data tiles + 1 al tile
    int nwave_blocks = (N + 3) / 4;
    int nodeBlocks = (N + 3) / 4;

    // ---- layer 1 ----
    k_gemm_lds<<<tm128 * tiles_n12, 256, 0, stream>>>(xb, W1T, hb, N, DIN, HC, tiles_n12, als, ald);
    k_aggr4f<true><<<4 * nodeBlocks, 256, 0, stream>>>(hb, als, ald, off, deg, csr, b1, act, N, nodeBlocks);

    // ---- layer 2 ----
    k_gemm_lds<<<tm128 * tiles_n12, 256, 0, stream>>>(act, W2T, hb, N, HC, HC, tiles_n12, als, ald);
    k_aggr4f<true><<<4 * nodeBlocks, 256, 0, stream>>>(hb, als, ald, off, deg, csr, b2, act, N, nodeBlocks);

    // ---- layer 3 (fp16 h path; Nc=64, al fused into GEMM epilogue) ----
    k_gemm<true, true><<<gemm_blocks(1), 256, 0, stream>>>(
        act, W3T, hb3, N, HC, DOUT, 1, as3, ad3, als, ald);
    k_aggr1c<<<nwave_blocks, 256, 0, stream>>>(hb3, als, ald, off, deg, csr, b3, (float*)d_out, N);
}